// Round 1
// baseline (318.377 us; speedup 1.0000x reference)
//
#include <hip/hip_runtime.h>

// Problem constants
#define B_    16
#define DIM   128
#define NPTS  16384
#define J_    16
#define K_    128
#define L_    128
#define R_    8
#define M1_   64

typedef float  f32x4 __attribute__((ext_vector_type(4)));
typedef short  s16x8 __attribute__((ext_vector_type(8)));
typedef unsigned short u16;
typedef u16 u16x8 __attribute__((ext_vector_type(8)));
typedef u16 u16x4 __attribute__((ext_vector_type(4)));

__device__ __forceinline__ u16 f2bf(float f) {
    unsigned u = __float_as_uint(f);
    u += 0x7FFFu + ((u >> 16) & 1u);          // round-nearest-even
    return (u16)(u >> 16);
}
#define MFMA16(a,b,c) __builtin_amdgcn_mfma_f32_16x16x32_bf16((a),(b),(c),0,0,0)

// Workspace byte offsets (34 MB total; ws is >=512 MB per harness fill size)
#define OFF_PARTA 0u           // 8 MB: stageA partials f32 [8][2048][128]; reused as Tt u16 [16][128][2048]
#define OFF_WBT   8388608u     // 4 MB: wbT u16 [128][16384]
#define OFF_BASB  12582912u    // 4 MB: basesb u16 [16384][128]
#define OFF_HKL   16777216u    // 0.5 MB: Hkl u16 [16][128][128]   ([j][k][l])
#define OFF_W2T   17301504u    // 0.5 MB: W2T u16 [128][2048]      ([o][j*128+i])
#define OFF_XHB   17825792u    // 0.5 MB: xhatb u16 [2048][128]
#define OFF_YB    18350080u    // 0.5 MB: yb u16 [2048][128]
#define OFF_YP    18874368u    // 16 MB: ypart f32 [16][16][128][128]

// ---------------------------------------------------------------------------
// Merged prep: one launch, range-dispatched by blockIdx (uniform per block).
//  [0,1024):     Hkl[j][k][l] = Do*Di*product + lowrank Q
//  [1024,2048):  W2T[o][j*128+i] = weights[i][o][j]
//  [2048,2176):  wbT[l][p] = bf16(wbases[p][l])   (LDS transpose)
//  [2176,4224):  basesb = bf16(bases)
__global__ __launch_bounds__(256) void k_prep(
    const float* __restrict__ product, const float* __restrict__ Do,
    const float* __restrict__ Di, const float* __restrict__ A,
    const float* __restrict__ Bm, const float* __restrict__ W,
    const float* __restrict__ wb, const float* __restrict__ bases,
    u16* __restrict__ Hkl, u16* __restrict__ W2T,
    u16* __restrict__ wbT, u16* __restrict__ basesb)
{
    __shared__ u16 sT[128][136];
    const int bid = blockIdx.x, t = threadIdx.x;
    if (bid < 1024) {
        int idx = (bid << 8) | t;
        int j = idx >> 14, k = (idx >> 7) & 127, l = idx & 127;
        float v = Do[j*K_ + k] * Di[j*L_ + l] * product[k*L_ + l];
        if (k < M1_ && l < M1_) {
            float q = 0.f;
            #pragma unroll
            for (int r = 0; r < R_; ++r)
                q += A[(j*R_ + r)*M1_ + k] * Bm[(j*R_ + r)*M1_ + l];
            v += q;
        }
        Hkl[idx] = f2bf(v);
    } else if (bid < 2048) {
        int idx = ((bid - 1024) << 8) | t;
        int o = idx >> 11, ji = idx & 2047, j = ji >> 7, i = ji & 127;
        W2T[idx] = f2bf(W[(i*DIM + o)*J_ + j]);
    } else if (bid < 2176) {
        const int p0 = (bid - 2048) * 128;
        #pragma unroll
        for (int it = 0; it < 16; ++it) {
            int idx = it*256 + t, row = idx >> 5, c4 = (idx & 31) * 4;
            float4 v = *(const float4*)(wb + (size_t)(p0+row)*L_ + c4);
            sT[c4+0][row] = f2bf(v.x); sT[c4+1][row] = f2bf(v.y);
            sT[c4+2][row] = f2bf(v.z); sT[c4+3][row] = f2bf(v.w);
        }
        __syncthreads();
        #pragma unroll
        for (int it = 0; it < 8; ++it) {
            int idx = it*256 + t, l = idx >> 4, pc = (idx & 15) * 8;
            *(u16x8*)(wbT + (size_t)l*NPTS + p0 + pc) = *(const u16x8*)&sT[l][pc];
        }
    } else {
        int i = (((bid - 2176) << 8) | t) * 4;
        float4 v = *(const float4*)(bases + i);
        u16x4 o4 = { f2bf(v.x), f2bf(v.y), f2bf(v.z), f2bf(v.w) };
        *(u16x4*)(basesb + i) = o4;
    }
}

// ---------------------------------------------------------------------------
// Stage A: part[ks][bi][l] = sum_{p in 2048-chunk} x[bi][p]*wbT[l][p]
// grid (32 m-tiles of 64, 8 k-splits), 512 thr (8 waves 2x4, wave-tile 32x32),
// BK=128, DOUBLE-BUFFERED: one barrier per chunk, next-chunk global loads
// issued before the MFMA cluster so they stay in flight across it.
__global__ __launch_bounds__(512) void k_stageA(
    const float* __restrict__ x, const u16* __restrict__ wbT,
    float* __restrict__ part)
{
    __shared__ u16 sA[2][64][136];    // [buf][m][p]
    __shared__ u16 sB[2][128][136];   // [buf][l][p]
    const int t = threadIdx.x, lane = t & 63, wave = t >> 6;
    const int quad = lane >> 4, l16 = lane & 15;
    const int wr = wave >> 2, wc = wave & 3;
    const int m0 = blockIdx.x * 64;
    const size_t pbase = (size_t)blockIdx.y * 2048;

    f32x4 acc[2][2] = {};
    const int ac4 = (t & 31) * 4, arr = t >> 5;    // x: 4 float4/thread
    const int bc8 = (t & 15) * 8, brr = t >> 4;    // wbT: 4 u16x8/thread

    // prologue: stage chunk 0 into buffer 0
    #pragma unroll
    for (int i = 0; i < 4; ++i) {
        int row = arr + 16*i;
        float4 v = *(const float4*)(x + (size_t)(m0+row)*NPTS + pbase + ac4);
        u16x4 h = { f2bf(v.x), f2bf(v.y), f2bf(v.z), f2bf(v.w) };
        *(u16x4*)&sA[0][row][ac4] = h;
    }
    #pragma unroll
    for (int i = 0; i < 4; ++i) {
        int row = brr + 32*i;
        *(u16x8*)&sB[0][row][bc8] =
            *(const u16x8*)(wbT + (size_t)row*NPTS + pbase + bc8);
    }

    int cur = 0;
    for (int c = 0; c < 16; ++c) {
        __syncthreads();                     // buf[cur] ready for all waves
        float4 vx[4]; u16x8 vb[4];
        if (c < 15) {                        // issue next-chunk loads EARLY
            const size_t pb = pbase + (size_t)(c+1)*128;
            #pragma unroll
            for (int i = 0; i < 4; ++i)
                vx[i] = *(const float4*)(x + (size_t)(m0+arr+16*i)*NPTS + pb + ac4);
            #pragma unroll
            for (int i = 0; i < 4; ++i)
                vb[i] = *(const u16x8*)(wbT + (size_t)(brr+32*i)*NPTS + pb + bc8);
        }
        #pragma unroll
        for (int ks = 0; ks < 4; ++ks) {
            int kb = ks*32 + quad*8;
            s16x8 a0 = *(const s16x8*)&sA[cur][wr*32      + l16][kb];
            s16x8 a1 = *(const s16x8*)&sA[cur][wr*32 + 16 + l16][kb];
            s16x8 b0 = *(const s16x8*)&sB[cur][wc*32      + l16][kb];
            s16x8 b1 = *(const s16x8*)&sB[cur][wc*32 + 16 + l16][kb];
            acc[0][0] = MFMA16(a0, b0, acc[0][0]);
            acc[0][1] = MFMA16(a0, b1, acc[0][1]);
            acc[1][0] = MFMA16(a1, b0, acc[1][0]);
            acc[1][1] = MFMA16(a1, b1, acc[1][1]);
        }
        if (c < 15) {                        // write next chunk to other buffer
            int nxt = cur ^ 1;
            #pragma unroll
            for (int i = 0; i < 4; ++i) {
                u16x4 h = { f2bf(vx[i].x), f2bf(vx[i].y), f2bf(vx[i].z), f2bf(vx[i].w) };
                *(u16x4*)&sA[nxt][arr+16*i][ac4] = h;
            }
            #pragma unroll
            for (int i = 0; i < 4; ++i)
                *(u16x8*)&sB[nxt][brr+32*i][bc8] = vb[i];
        }
        cur ^= 1;
    }

    float* po = part + (size_t)blockIdx.y * (2048*128);
    #pragma unroll
    for (int mt = 0; mt < 2; ++mt)
      #pragma unroll
      for (int r = 0; r < 4; ++r) {
        int row = m0 + wr*32 + mt*16 + quad*4 + r;
        #pragma unroll
        for (int nt = 0; nt < 2; ++nt) {
            int col = wc*32 + nt*16 + l16;
            po[(size_t)row*128 + col] = acc[mt][nt][r];
        }
      }
}

// xhatb[bi][l] = bf16( sum of 8 partials ), float4-vectorized
__global__ __launch_bounds__(256) void k_reduceA(
    const float* __restrict__ part, u16* __restrict__ xhatb)
{
    const float4* p4 = (const float4*)part;
    int i = blockIdx.x * 256 + threadIdx.x;          // 65536 float4 elems
    float4 s = {0.f, 0.f, 0.f, 0.f};
    #pragma unroll
    for (int p = 0; p < 8; ++p) {
        float4 v = p4[(size_t)p*65536 + i];
        s.x += v.x; s.y += v.y; s.z += v.z; s.w += v.w;
    }
    u16x4 o4 = { f2bf(s.x), f2bf(s.y), f2bf(s.z), f2bf(s.w) };
    *(u16x4*)(xhatb + (size_t)i*4) = o4;
}

// ---------------------------------------------------------------------------
// mix1: Tt[b][k][j*128+i] = sum_l Hkl[j][k][l] * xhatb[b*128+i][l]
// grid (16 b, 16 j, 2 k-halves), 256 thr (4 waves 2x2, wave-tile 32x64),
// 52 KB LDS -> 3 blocks/CU for latency hiding.
__global__ __launch_bounds__(256) void k_mix1(
    const u16* __restrict__ Hkl, const u16* __restrict__ xhatb,
    u16* __restrict__ Tt)
{
    __shared__ u16 sA[64][136];    // [k][l]
    __shared__ u16 sB[128][136];   // [i][l]
    const int t = threadIdx.x, lane = t & 63, wave = t >> 6;
    const int quad = lane >> 4, l16 = lane & 15;
    const int wr = wave >> 1, wc = wave & 1;
    const int b = blockIdx.x, j = blockIdx.y, kh = blockIdx.z;
    const u16* ha = Hkl + j*16384 + kh*64*128;
    const u16* xb = xhatb + b*16384;

    const int c8 = (t & 15)*8, rr = t >> 4;
    #pragma unroll
    for (int i = 0; i < 4; ++i) {
        int row = rr + 16*i;
        *(u16x8*)&sA[row][c8] = *(const u16x8*)(ha + row*128 + c8);
    }
    #pragma unroll
    for (int i = 0; i < 8; ++i) {
        int row = rr + 16*i;
        *(u16x8*)&sB[row][c8] = *(const u16x8*)(xb + row*128 + c8);
    }
    __syncthreads();

    f32x4 acc[2][4] = {};
    #pragma unroll
    for (int ks = 0; ks < 4; ++ks) {
        int kb = ks*32 + quad*8;
        s16x8 a[2], bf[4];
        #pragma unroll
        for (int mt = 0; mt < 2; ++mt) a[mt]  = *(const s16x8*)&sA[wr*32 + mt*16 + l16][kb];
        #pragma unroll
        for (int nt = 0; nt < 4; ++nt) bf[nt] = *(const s16x8*)&sB[wc*64 + nt*16 + l16][kb];
        #pragma unroll
        for (int mt = 0; mt < 2; ++mt)
            #pragma unroll
            for (int nt = 0; nt < 4; ++nt)
                acc[mt][nt] = MFMA16(a[mt], bf[nt], acc[mt][nt]);
    }
    u16* to = Tt + (size_t)b*262144 + (j << 7);
    #pragma unroll
    for (int mt = 0; mt < 2; ++mt)
      #pragma unroll
      for (int r = 0; r < 4; ++r) {
        int k = kh*64 + wr*32 + mt*16 + quad*4 + r;
        #pragma unroll
        for (int nt = 0; nt < 4; ++nt) {
            int i = wc*64 + nt*16 + l16;
            to[(size_t)k*2048 + i] = f2bf(acc[mt][nt][r]);
        }
      }
}

// ---------------------------------------------------------------------------
// mix2: ypart[c][b][o][k] = sum_{ji in 128-chunk c} W2T[o][ji] * Tt[b][k][ji]
// grid (16 b, 16 c, 2 o-halves), 256 thr (2x2 waves, wave-tile 32x64),
// 52 KB LDS -> 3 blocks/CU.
__global__ __launch_bounds__(256) void k_mix2(
    const u16* __restrict__ W2T, const u16* __restrict__ Tt,
    float* __restrict__ ypart)
{
    __shared__ u16 sA[64][136];    // [o][ji]
    __shared__ u16 sB[128][136];   // [k][ji]
    const int t = threadIdx.x, lane = t & 63, wave = t >> 6;
    const int quad = lane >> 4, l16 = lane & 15;
    const int wr = wave >> 1, wc = wave & 1;
    const int b = blockIdx.x, c = blockIdx.y, oh = blockIdx.z;
    const int ji0 = c * 128;
    const u16* tb = Tt + (size_t)b*262144;

    const int c8 = (t & 15)*8, rr = t >> 4;
    #pragma unroll
    for (int i = 0; i < 4; ++i) {
        int row = rr + 16*i;
        *(u16x8*)&sA[row][c8] = *(const u16x8*)(W2T + (size_t)(oh*64+row)*2048 + ji0 + c8);
    }
    #pragma unroll
    for (int i = 0; i < 8; ++i) {
        int row = rr + 16*i;
        *(u16x8*)&sB[row][c8] = *(const u16x8*)(tb + (size_t)row*2048 + ji0 + c8);
    }
    __syncthreads();

    f32x4 acc[2][4] = {};
    #pragma unroll
    for (int ks = 0; ks < 4; ++ks) {
        int kb = ks*32 + quad*8;
        s16x8 a[2], bf[4];
        #pragma unroll
        for (int mt = 0; mt < 2; ++mt) a[mt]  = *(const s16x8*)&sA[wr*32 + mt*16 + l16][kb];
        #pragma unroll
        for (int nt = 0; nt < 4; ++nt) bf[nt] = *(const s16x8*)&sB[wc*64 + nt*16 + l16][kb];
        #pragma unroll
        for (int mt = 0; mt < 2; ++mt)
            #pragma unroll
            for (int nt = 0; nt < 4; ++nt)
                acc[mt][nt] = MFMA16(a[mt], bf[nt], acc[mt][nt]);
    }
    float* yo = ypart + ((size_t)(c*16 + b) << 14);
    #pragma unroll
    for (int mt = 0; mt < 2; ++mt)
      #pragma unroll
      for (int r = 0; r < 4; ++r) {
        int o = oh*64 + wr*32 + mt*16 + quad*4 + r;
        #pragma unroll
        for (int nt = 0; nt < 4; ++nt) {
            int k = wc*64 + nt*16 + l16;
            yo[(size_t)o*128 + k] = acc[mt][nt][r];
        }
      }
}

// yb[bo][k] = bf16( sum of 16 partials ), float4-vectorized
__global__ __launch_bounds__(256) void k_reduceY(
    const float* __restrict__ part, u16* __restrict__ yb)
{
    const float4* p4 = (const float4*)part;
    int i = blockIdx.x * 256 + threadIdx.x;          // 65536 float4 elems
    float4 s = {0.f, 0.f, 0.f, 0.f};
    #pragma unroll
    for (int p = 0; p < 16; ++p) {
        float4 v = p4[(size_t)p*65536 + i];
        s.x += v.x; s.y += v.y; s.z += v.z; s.w += v.w;
    }
    u16x4 o4 = { f2bf(s.x), f2bf(s.y), f2bf(s.z), f2bf(s.w) };
    *(u16x4*)(yb + (size_t)i*4) = o4;
}

// ---------------------------------------------------------------------------
// Stage E: out[bo][p] = sum_k yb[bo][k] * basesb[p][k]
// grid (16 bo-tiles, 128 p-tiles), 256 thr, single-shot K=128
__global__ __launch_bounds__(256) void k_stageE(
    const u16* __restrict__ yb, const u16* __restrict__ basesb,
    float* __restrict__ out)
{
    __shared__ u16 sA[128][136];   // [bo][k]
    __shared__ u16 sB[128][136];   // [p][k]
    const int t = threadIdx.x, lane = t & 63, wave = t >> 6;
    const int quad = lane >> 4, l16 = lane & 15;
    const int wr = wave >> 1, wc = wave & 1;
    const int bo0 = blockIdx.x * 128, p0 = blockIdx.y * 128;

    const int c8 = (t & 15)*8, rr = t >> 4;
    #pragma unroll
    for (int i = 0; i < 8; ++i) {
        int row = rr + 16*i;
        *(u16x8*)&sA[row][c8] = *(const u16x8*)(yb     + (size_t)(bo0+row)*128 + c8);
        *(u16x8*)&sB[row][c8] = *(const u16x8*)(basesb + (size_t)(p0 +row)*128 + c8);
    }
    __syncthreads();

    f32x4 acc[4][4] = {};
    #pragma unroll
    for (int ks = 0; ks < 4; ++ks) {
        int kb = ks*32 + quad*8;
        s16x8 a[4], bf[4];
        #pragma unroll
        for (int mt = 0; mt < 4; ++mt) a[mt]  = *(const s16x8*)&sA[wr*64 + mt*16 + l16][kb];
        #pragma unroll
        for (int nt = 0; nt < 4; ++nt) bf[nt] = *(const s16x8*)&sB[wc*64 + nt*16 + l16][kb];
        #pragma unroll
        for (int mt = 0; mt < 4; ++mt)
            #pragma unroll
            for (int nt = 0; nt < 4; ++nt)
                acc[mt][nt] = MFMA16(a[mt], bf[nt], acc[mt][nt]);
    }
    #pragma unroll
    for (int mt = 0; mt < 4; ++mt)
      #pragma unroll
      for (int r = 0; r < 4; ++r) {
        size_t row = bo0 + wr*64 + mt*16 + quad*4 + r;
        #pragma unroll
        for (int nt = 0; nt < 4; ++nt) {
            int p = p0 + wc*64 + nt*16 + l16;
            out[row*NPTS + p] = acc[mt][nt][r];
        }
      }
}

// ---------------------------------------------------------------------------
extern "C" void kernel_launch(void* const* d_in, const int* in_sizes, int n_in,
                              void* d_out, int out_size, void* d_ws, size_t ws_size,
                              hipStream_t stream) {
    (void)in_sizes; (void)n_in; (void)out_size; (void)ws_size;
    const float* x       = (const float*)d_in[0];
    const float* bases   = (const float*)d_in[1];
    const float* wbases  = (const float*)d_in[2];
    const float* product = (const float*)d_in[3];
    const float* Do      = (const float*)d_in[4];
    const float* Di      = (const float*)d_in[5];
    const float* A       = (const float*)d_in[6];
    const float* Bm      = (const float*)d_in[7];
    const float* W       = (const float*)d_in[8];

    char* ws = (char*)d_ws;
    float* partA  = (float*)(ws + OFF_PARTA);
    u16*   Tt     = (u16*)  (ws + OFF_PARTA);   // reuses partA after reduceA
    u16*   wbT    = (u16*)  (ws + OFF_WBT);
    u16*   basesb = (u16*)  (ws + OFF_BASB);
    u16*   Hkl    = (u16*)  (ws + OFF_HKL);
    u16*   W2T    = (u16*)  (ws + OFF_W2T);
    u16*   xhatb  = (u16*)  (ws + OFF_XHB);
    u16*   yb     = (u16*)  (ws + OFF_YB);
    float* ypart  = (float*)(ws + OFF_YP);

    k_prep   <<<4224, 256, 0, stream>>>(product, Do, Di, A, Bm, W, wbases, bases,
                                        Hkl, W2T, wbT, basesb);
    k_stageA <<<dim3(32, 8), 512, 0, stream>>>(x, wbT, partA);
    k_reduceA<<<256, 256, 0, stream>>>(partA, xhatb);
    k_mix1   <<<dim3(16, 16, 2), 256, 0, stream>>>(Hkl, xhatb, Tt);
    k_mix2   <<<dim3(16, 16, 2), 256, 0, stream>>>(W2T, Tt, ypart);
    k_reduceY<<<256, 256, 0, stream>>>(ypart, yb);
    k_stageE <<<dim3(16, 128), 256, 0, stream>>>(yb, basesb, (float*)d_out);
}

// Round 2
// 311.233 us; speedup vs baseline: 1.0230x; 1.0230x over previous
//
#include <hip/hip_runtime.h>

// Problem constants
#define B_    16
#define DIM   128
#define NPTS  16384
#define J_    16
#define K_    128
#define L_    128
#define R_    8
#define M1_   64

typedef float  f32x4 __attribute__((ext_vector_type(4)));
typedef short  s16x8 __attribute__((ext_vector_type(8)));
typedef unsigned short u16;
typedef u16 u16x8 __attribute__((ext_vector_type(8)));
typedef u16 u16x4 __attribute__((ext_vector_type(4)));

__device__ __forceinline__ u16 f2bf(float f) {
    unsigned u = __float_as_uint(f);
    u += 0x7FFFu + ((u >> 16) & 1u);          // round-nearest-even
    return (u16)(u >> 16);
}
#define MFMA16(a,b,c) __builtin_amdgcn_mfma_f32_16x16x32_bf16((a),(b),(c),0,0,0)

// Workspace byte offsets (ws is >=512 MB per harness fill size)
#define OFF_PARTA 0u           // 8 MB: stageA partials f32 [8][2048][128]
#define OFF_WBT   8388608u     // 4 MB: wbT u16 [128][16384]
#define OFF_BASB  12582912u    // 4 MB: basesb u16 [16384][128]
#define OFF_HKL   16777216u    // 0.5 MB: Hkl u16 [16][128][128]   ([j][k][l])
#define OFF_W2T   17301504u    // 0.5 MB: W2T u16 [128][2048]      ([o][j*128+i])
#define OFF_XHB   17825792u    // 0.5 MB: xhatb u16 [2048][128]
#define OFF_YB    18350080u    // 0.5 MB: yb u16 [2048][128]

// ---------------------------------------------------------------------------
// Merged prep: one launch, range-dispatched by blockIdx (uniform per block).
__global__ __launch_bounds__(256) void k_prep(
    const float* __restrict__ product, const float* __restrict__ Do,
    const float* __restrict__ Di, const float* __restrict__ A,
    const float* __restrict__ Bm, const float* __restrict__ W,
    const float* __restrict__ wb, const float* __restrict__ bases,
    u16* __restrict__ Hkl, u16* __restrict__ W2T,
    u16* __restrict__ wbT, u16* __restrict__ basesb)
{
    __shared__ u16 sT[128][136];
    const int bid = blockIdx.x, t = threadIdx.x;
    if (bid < 1024) {
        int idx = (bid << 8) | t;
        int j = idx >> 14, k = (idx >> 7) & 127, l = idx & 127;
        float v = Do[j*K_ + k] * Di[j*L_ + l] * product[k*L_ + l];
        if (k < M1_ && l < M1_) {
            float q = 0.f;
            #pragma unroll
            for (int r = 0; r < R_; ++r)
                q += A[(j*R_ + r)*M1_ + k] * Bm[(j*R_ + r)*M1_ + l];
            v += q;
        }
        Hkl[idx] = f2bf(v);
    } else if (bid < 2048) {
        int idx = ((bid - 1024) << 8) | t;
        int o = idx >> 11, ji = idx & 2047, j = ji >> 7, i = ji & 127;
        W2T[idx] = f2bf(W[(i*DIM + o)*J_ + j]);
    } else if (bid < 2176) {
        const int p0 = (bid - 2048) * 128;
        #pragma unroll
        for (int it = 0; it < 16; ++it) {
            int idx = it*256 + t, row = idx >> 5, c4 = (idx & 31) * 4;
            float4 v = *(const float4*)(wb + (size_t)(p0+row)*L_ + c4);
            sT[c4+0][row] = f2bf(v.x); sT[c4+1][row] = f2bf(v.y);
            sT[c4+2][row] = f2bf(v.z); sT[c4+3][row] = f2bf(v.w);
        }
        __syncthreads();
        #pragma unroll
        for (int it = 0; it < 8; ++it) {
            int idx = it*256 + t, l = idx >> 4, pc = (idx & 15) * 8;
            *(u16x8*)(wbT + (size_t)l*NPTS + p0 + pc) = *(const u16x8*)&sT[l][pc];
        }
    } else {
        int i = (((bid - 2176) << 8) | t) * 4;
        float4 v = *(const float4*)(bases + i);
        u16x4 o4 = { f2bf(v.x), f2bf(v.y), f2bf(v.z), f2bf(v.w) };
        *(u16x4*)(basesb + i) = o4;
    }
}

// ---------------------------------------------------------------------------
// Stage A: part[ks][bi][l] = sum_{p in 2048-chunk} x[bi][p]*wbT[l][p]
// grid (32 m-tiles of 64, 8 k-splits), 512 thr (8 waves 2x4, wave-tile 32x32).
// Single-buffer 51 KB LDS -> 3 blocks/CU (TLP), plus T14 early-issue:
// next-chunk global loads are issued before the MFMA cluster and written
// to LDS after the trailing barrier.
__global__ __launch_bounds__(512) void k_stageA(
    const float* __restrict__ x, const u16* __restrict__ wbT,
    float* __restrict__ part)
{
    __shared__ u16 sA[64][136];    // [m][p]
    __shared__ u16 sB[128][136];   // [l][p]
    const int t = threadIdx.x, lane = t & 63, wave = t >> 6;
    const int quad = lane >> 4, l16 = lane & 15;
    const int wr = wave >> 2, wc = wave & 3;
    const int m0 = blockIdx.x * 64;
    const size_t pbase = (size_t)blockIdx.y * 2048;

    f32x4 acc[2][2] = {};
    const int ac4 = (t & 31) * 4, arr = t >> 5;    // x: 4 float4/thread
    const int bc8 = (t & 15) * 8, brr = t >> 4;    // wbT: 4 u16x8/thread

    float4 vx[4]; u16x8 vb[4];
    // prologue: chunk 0
    #pragma unroll
    for (int i = 0; i < 4; ++i)
        vx[i] = *(const float4*)(x + (size_t)(m0+arr+16*i)*NPTS + pbase + ac4);
    #pragma unroll
    for (int i = 0; i < 4; ++i)
        vb[i] = *(const u16x8*)(wbT + (size_t)(brr+32*i)*NPTS + pbase + bc8);
    #pragma unroll
    for (int i = 0; i < 4; ++i) {
        u16x4 h = { f2bf(vx[i].x), f2bf(vx[i].y), f2bf(vx[i].z), f2bf(vx[i].w) };
        *(u16x4*)&sA[arr+16*i][ac4] = h;
    }
    #pragma unroll
    for (int i = 0; i < 4; ++i)
        *(u16x8*)&sB[brr+32*i][bc8] = vb[i];

    for (int c = 0; c < 16; ++c) {
        __syncthreads();                     // chunk c visible to all waves
        if (c < 15) {                        // issue next-chunk loads EARLY
            const size_t pb = pbase + (size_t)(c+1)*128;
            #pragma unroll
            for (int i = 0; i < 4; ++i)
                vx[i] = *(const float4*)(x + (size_t)(m0+arr+16*i)*NPTS + pb + ac4);
            #pragma unroll
            for (int i = 0; i < 4; ++i)
                vb[i] = *(const u16x8*)(wbT + (size_t)(brr+32*i)*NPTS + pb + bc8);
        }
        #pragma unroll
        for (int ks = 0; ks < 4; ++ks) {
            int kb = ks*32 + quad*8;
            s16x8 a0 = *(const s16x8*)&sA[wr*32      + l16][kb];
            s16x8 a1 = *(const s16x8*)&sA[wr*32 + 16 + l16][kb];
            s16x8 b0 = *(const s16x8*)&sB[wc*32      + l16][kb];
            s16x8 b1 = *(const s16x8*)&sB[wc*32 + 16 + l16][kb];
            acc[0][0] = MFMA16(a0, b0, acc[0][0]);
            acc[0][1] = MFMA16(a0, b1, acc[0][1]);
            acc[1][0] = MFMA16(a1, b0, acc[1][0]);
            acc[1][1] = MFMA16(a1, b1, acc[1][1]);
        }
        __syncthreads();                     // all waves done reading chunk c
        if (c < 15) {
            #pragma unroll
            for (int i = 0; i < 4; ++i) {
                u16x4 h = { f2bf(vx[i].x), f2bf(vx[i].y), f2bf(vx[i].z), f2bf(vx[i].w) };
                *(u16x4*)&sA[arr+16*i][ac4] = h;
            }
            #pragma unroll
            for (int i = 0; i < 4; ++i)
                *(u16x8*)&sB[brr+32*i][bc8] = vb[i];
        }
    }

    float* po = part + (size_t)blockIdx.y * (2048*128);
    #pragma unroll
    for (int mt = 0; mt < 2; ++mt)
      #pragma unroll
      for (int r = 0; r < 4; ++r) {
        int row = m0 + wr*32 + mt*16 + quad*4 + r;
        #pragma unroll
        for (int nt = 0; nt < 2; ++nt) {
            int col = wc*32 + nt*16 + l16;
            po[(size_t)row*128 + col] = acc[mt][nt][r];
        }
      }
}

// xhatb[bi][l] = bf16( sum of 8 partials ), float4-vectorized
__global__ __launch_bounds__(256) void k_reduceA(
    const float* __restrict__ part, u16* __restrict__ xhatb)
{
    const float4* p4 = (const float4*)part;
    int i = blockIdx.x * 256 + threadIdx.x;          // 65536 float4 elems
    float4 s = {0.f, 0.f, 0.f, 0.f};
    #pragma unroll
    for (int p = 0; p < 8; ++p) {
        float4 v = p4[(size_t)p*65536 + i];
        s.x += v.x; s.y += v.y; s.z += v.z; s.w += v.w;
    }
    u16x4 o4 = { f2bf(s.x), f2bf(s.y), f2bf(s.z), f2bf(s.w) };
    *(u16x4*)(xhatb + (size_t)i*4) = o4;
}

// ---------------------------------------------------------------------------
// Fused mix: yb[b*128+o][k] = bf16( sum_j sum_i W2T[o][j*128+i] *
//                                  (sum_l Hkl[j][k][l]*xhatb[b*128+i][l]) )
// grid (16 b, 4 kq, 4 oq), 256 thr (4 waves 2x2).
// Per j: GEMM1 T_j[k32][i128] = H_j x xh^T  (LDS round-trip, bf16),
//        GEMM2 acc2[o16][k16] += W_j x T_j  (register accumulation over j).
// H/W double-buffered in LDS (2 barriers per j, parity buffers).
// Replaces the former mix1 -> Tt(8.4MB) -> mix2 -> ypart(16MB) -> reduceY.
__global__ __launch_bounds__(256) void k_mix(
    const u16* __restrict__ Hkl, const u16* __restrict__ W2T,
    const u16* __restrict__ xhatb, u16* __restrict__ yb)
{
    __shared__ u16 sXh[128][136];    // [i][l]
    __shared__ u16 sH[2][32][136];   // [k][l]
    __shared__ u16 sW[2][32][136];   // [o][i]
    __shared__ u16 sT[32][136];      // [k][i]
    const int t = threadIdx.x, lane = t & 63, wave = t >> 6;
    const int quad = lane >> 4, l16 = lane & 15;
    const int wr = wave >> 1, wc = wave & 1;
    const int b = blockIdx.x, kq = blockIdx.y, oq = blockIdx.z;

    const int c8 = (t & 15) * 8, rr = t >> 4;
    // prologue staging: xh (once), H/W for j=0
    #pragma unroll
    for (int i = 0; i < 8; ++i) {
        int row = rr + 16*i;
        *(u16x8*)&sXh[row][c8] =
            *(const u16x8*)(xhatb + (size_t)b*16384 + row*128 + c8);
    }
    #pragma unroll
    for (int i = 0; i < 2; ++i) {
        int row = rr + 16*i;
        *(u16x8*)&sH[0][row][c8] =
            *(const u16x8*)(Hkl + (size_t)(kq*32 + row)*128 + c8);
        *(u16x8*)&sW[0][row][c8] =
            *(const u16x8*)(W2T + (size_t)(oq*32 + row)*2048 + c8);
    }

    f32x4 acc2 = {};
    for (int j = 0; j < 16; ++j) {
        const int cur = j & 1, nxt = cur ^ 1;
        __syncthreads();       // (1) sH/sW[cur] visible; prev GEMM2 done with sT
        // GEMM1: T[k32][i128] = H_j[k32][l] x xh[i128][l]
        f32x4 acc1[4] = {};
        #pragma unroll
        for (int ks = 0; ks < 4; ++ks) {
            int kb = ks*32 + quad*8;
            s16x8 a = *(const s16x8*)&sH[cur][wr*16 + l16][kb];
            #pragma unroll
            for (int nt = 0; nt < 4; ++nt) {
                s16x8 bf = *(const s16x8*)&sXh[wc*64 + nt*16 + l16][kb];
                acc1[nt] = MFMA16(a, bf, acc1[nt]);
            }
        }
        u16x8 hv[2], wv[2];
        if (j < 15) {          // T14: issue next-j loads while MFMA results settle
            #pragma unroll
            for (int i = 0; i < 2; ++i) {
                int row = rr + 16*i;
                hv[i] = *(const u16x8*)(Hkl +
                        ((size_t)(j+1)*128 + kq*32 + row)*128 + c8);
                wv[i] = *(const u16x8*)(W2T +
                        (size_t)(oq*32 + row)*2048 + (j+1)*128 + c8);
            }
        }
        #pragma unroll
        for (int nt = 0; nt < 4; ++nt)
            #pragma unroll
            for (int r = 0; r < 4; ++r)
                sT[wr*16 + quad*4 + r][wc*64 + nt*16 + l16] = f2bf(acc1[nt][r]);
        __syncthreads();       // (2) sT visible; all waves past GEMM1
        if (j < 15) {          // write next j into parity buffer (not being read)
            #pragma unroll
            for (int i = 0; i < 2; ++i) {
                int row = rr + 16*i;
                *(u16x8*)&sH[nxt][row][c8] = hv[i];
                *(u16x8*)&sW[nxt][row][c8] = wv[i];
            }
        }
        // GEMM2: acc2 += W_j[o32][i] x T[k32][i]  (wave tile 16x16)
        #pragma unroll
        for (int ks = 0; ks < 4; ++ks) {
            int kb = ks*32 + quad*8;
            s16x8 a2 = *(const s16x8*)&sW[cur][wr*16 + l16][kb];
            s16x8 b2 = *(const s16x8*)&sT[wc*16 + l16][kb];
            acc2 = MFMA16(a2, b2, acc2);
        }
    }
    #pragma unroll
    for (int r = 0; r < 4; ++r) {
        int o = oq*32 + wr*16 + quad*4 + r;
        int k = kq*32 + wc*16 + l16;
        yb[((size_t)b*128 + o)*128 + k] = f2bf(acc2[r]);
    }
}

// ---------------------------------------------------------------------------
// Stage E: out[bo][p] = sum_k yb[bo][k] * basesb[p][k]
// grid (16 bo-tiles, 128 p-tiles), 256 thr, single-shot K=128
__global__ __launch_bounds__(256) void k_stageE(
    const u16* __restrict__ yb, const u16* __restrict__ basesb,
    float* __restrict__ out)
{
    __shared__ u16 sA[128][136];   // [bo][k]
    __shared__ u16 sB[128][136];   // [p][k]
    const int t = threadIdx.x, lane = t & 63, wave = t >> 6;
    const int quad = lane >> 4, l16 = lane & 15;
    const int wr = wave >> 1, wc = wave & 1;
    const int bo0 = blockIdx.x * 128, p0 = blockIdx.y * 128;

    const int c8 = (t & 15)*8, rr = t >> 4;
    #pragma unroll
    for (int i = 0; i < 8; ++i) {
        int row = rr + 16*i;
        *(u16x8*)&sA[row][c8] = *(const u16x8*)(yb     + (size_t)(bo0+row)*128 + c8);
        *(u16x8*)&sB[row][c8] = *(const u16x8*)(basesb + (size_t)(p0 +row)*128 + c8);
    }
    __syncthreads();

    f32x4 acc[4][4] = {};
    #pragma unroll
    for (int ks = 0; ks < 4; ++ks) {
        int kb = ks*32 + quad*8;
        s16x8 a[4], bf[4];
        #pragma unroll
        for (int mt = 0; mt < 4; ++mt) a[mt]  = *(const s16x8*)&sA[wr*64 + mt*16 + l16][kb];
        #pragma unroll
        for (int nt = 0; nt < 4; ++nt) bf[nt] = *(const s16x8*)&sB[wc*64 + nt*16 + l16][kb];
        #pragma unroll
        for (int mt = 0; mt < 4; ++mt)
            #pragma unroll
            for (int nt = 0; nt < 4; ++nt)
                acc[mt][nt] = MFMA16(a[mt], bf[nt], acc[mt][nt]);
    }
    #pragma unroll
    for (int mt = 0; mt < 4; ++mt)
      #pragma unroll
      for (int r = 0; r < 4; ++r) {
        size_t row = bo0 + wr*64 + mt*16 + quad*4 + r;
        #pragma unroll
        for (int nt = 0; nt < 4; ++nt) {
            int p = p0 + wc*64 + nt*16 + l16;
            out[row*NPTS + p] = acc[mt][nt][r];
        }
      }
}

// ---------------------------------------------------------------------------
extern "C" void kernel_launch(void* const* d_in, const int* in_sizes, int n_in,
                              void* d_out, int out_size, void* d_ws, size_t ws_size,
                              hipStream_t stream) {
    (void)in_sizes; (void)n_in; (void)out_size; (void)ws_size;
    const float* x       = (const float*)d_in[0];
    const float* bases   = (const float*)d_in[1];
    const float* wbases  = (const float*)d_in[2];
    const float* product = (const float*)d_in[3];
    const float* Do      = (const float*)d_in[4];
    const float* Di      = (const float*)d_in[5];
    const float* A       = (const float*)d_in[6];
    const float* Bm      = (const float*)d_in[7];
    const float* W       = (const float*)d_in[8];

    char* ws = (char*)d_ws;
    float* partA  = (float*)(ws + OFF_PARTA);
    u16*   wbT    = (u16*)  (ws + OFF_WBT);
    u16*   basesb = (u16*)  (ws + OFF_BASB);
    u16*   Hkl    = (u16*)  (ws + OFF_HKL);
    u16*   W2T    = (u16*)  (ws + OFF_W2T);
    u16*   xhatb  = (u16*)  (ws + OFF_XHB);
    u16*   yb     = (u16*)  (ws + OFF_YB);

    k_prep   <<<4224, 256, 0, stream>>>(product, Do, Di, A, Bm, W, wbases, bases,
                                        Hkl, W2T, wbT, basesb);
    k_stageA <<<dim3(32, 8), 512, 0, stream>>>(x, wbT, partA);
    k_reduceA<<<256, 256, 0, stream>>>(partA, xhatb);
    k_mix    <<<dim3(16, 4, 4), 256, 0, stream>>>(Hkl, W2T, xhatb, yb);
    k_stageE <<<dim3(16, 128), 256, 0, stream>>>(yb, basesb, (float*)d_out);
}